// Round 9
// baseline (271.820 us; speedup 1.0000x reference)
//
#include <hip/hip_runtime.h>

// Problem constants (fixed by setup_inputs)
#define B_    8
#define D_    4
#define H_    640
#define W_    640
#define HW_   (H_ * W_)      // 409600
#define L_    8
#define NL    (L_ - 1)       // labels 1..7
#define BLOCK 256
#define VITER 4              // float4 iterations per thread -> 16 px/thread
#define PXB   (BLOCK * 4 * VITER)           // 4096 px per block
#define GRIDX (HW_ / PXB)                   // 100 -> grid (100,8) = 800 blocks

__device__ __forceinline__ void gatom_add(float* p, float v) {
    unsafeAtomicAdd(p, v);   // global_atomic_add_f32
}
__device__ __forceinline__ int aload_i(const int* p) {
    return __hip_atomic_load(p, __ATOMIC_ACQUIRE, __HIP_MEMORY_SCOPE_AGENT);
}
__device__ __forceinline__ float aload_f(const float* p) {
    return __hip_atomic_load(p, __ATOMIC_ACQUIRE, __HIP_MEMORY_SCOPE_AGENT);
}
__device__ __forceinline__ float4 gload4f(const float* p) {
    float4 r;
    asm volatile("global_load_dwordx4 %0, %1, off" : "=v"(r) : "v"(p));
    return r;
}
__device__ __forceinline__ int4 gload4i(const int* p) {
    int4 r;
    asm volatile("global_load_dwordx4 %0, %1, off" : "=v"(r) : "v"(p));
    return r;
}
#define WAITCNT(n) asm volatile("s_waitcnt vmcnt(" #n ")"); \
                   __builtin_amdgcn_sched_barrier(0)

// ---------------------------------------------------------------------------
// ws layout (4-byte elements):
//   int   firstIdx [64] @0     int secondIdx[64] @64
//   int   cntf_i   [64] @128   int cntk_i   [64] @192
//   float sumemb  [256] @256   float sumvalb [8] @512
//   int   barCnt   [8]  @544   int barFlag  [8]  @552
// (lblpack eliminated: labels live in 2 registers across the barrier)
// ---------------------------------------------------------------------------
__global__ void k_init(int* ib) {
    int t = threadIdx.x;
    if (t < 128) ib[t] = HW_;        // firstIdx + secondIdx
    ib[128 + t] = 0;                 // 128..383
    if (t < 176) ib[384 + t] = 0;    // 384..559 (sums, sumvalb, barriers)
}

// ---------------------------------------------------------------------------
// K_FUSED (R9) = R8 pass1 + per-image software barrier (R5/R6-proven) +
// R8 pass3 body with labels carried in 2 REGISTERS (lpLo/lpHi) and emb
// RE-READ from L3 in phase 2.
//  R5/R6 lesson: 64 E-regs across the barrier -> wholesale scratch spill.
//  Carrying only 2 regs cannot spill. Gains vs 2-kernel split:
//   - lblpack round-trip gone (1.6MB write + 1.6MB read)
//   - per-image barrier: image b's phase 2 starts when image b's stats are
//     done, filling the ~25% straggler tail (occupancy 22.6% vs 39%)
//   - one launch gap removed
//  Barrier safety: VGPR ~60 -> >=4 blocks/CU capacity; 800 co-resident.
//  Phase 2 reads stats with agent-scope atomic loads (cross-XCD L2, G16).
// ---------------------------------------------------------------------------
__global__ __attribute__((amdgpu_flat_work_group_size(BLOCK, BLOCK),
                          amdgpu_waves_per_eu(4, 4)))
void k_fused(
        const float* __restrict__ emb, const int* __restrict__ inst,
        const float* __restrict__ kern, const float* __restrict__ tmask,
        int* __restrict__ firstIdx, int* __restrict__ secondIdx,
        int* __restrict__ cntf_i, int* __restrict__ cntk_i,
        float* __restrict__ sumemb, float* __restrict__ sumvalb,
        int* __restrict__ barCnt, int* __restrict__ barFlag) {
    __shared__ int    sCnt[L_];      // cf<<16 | ck
    __shared__ float  sSum[L_ * D_];
    __shared__ int    sM1[L_], sM2[L_];
    __shared__ float4 sMean[L_];
    __shared__ float  sCd[L_], sInv[L_];
    __shared__ float  sAcc;

    const int tid  = threadIdx.x;
    const int lane = tid & 63;
    if (tid < L_) { sCnt[tid] = 0; sM1[tid] = HW_; sM2[tid] = HW_; }
    if (tid < L_ * D_) sSum[tid] = 0.f;
    __syncthreads();

    const int b = blockIdx.y;
    const int blockbase = blockIdx.x * PXB;
    const float* embb = emb + (size_t)b * D_ * HW_;
    const int base = b * HW_;
    const int o0 = blockbase + tid * 4;

    // ---- cluster A: 12 mask loads (oldest), then 8 emb half-0 loads ----
    int4 LB[VITER]; float4 TM[VITER], KN[VITER];
    #pragma unroll
    for (int it = 0; it < VITER; ++it)
        LB[it] = gload4i(inst + base + o0 + it * (BLOCK * 4));
    #pragma unroll
    for (int it = 0; it < VITER; ++it)
        TM[it] = gload4f(tmask + base + o0 + it * (BLOCK * 4));
    #pragma unroll
    for (int it = 0; it < VITER; ++it)
        KN[it] = gload4f(kern + base + o0 + it * (BLOCK * 4));
    float4 E0[2][D_];                // px 0..7
    #pragma unroll
    for (int s = 0; s < 2; ++s)
        #pragma unroll
        for (int d = 0; d < D_; ++d)
            E0[s][d] = gload4f(embb + d * HW_ + o0 + s * (BLOCK * 4));

    WAITCNT(8);                      // 20 issued, <=8 out -> all 12 masks done

    // ---- bitplanes + packed labels for all 16 px ----
    int bp0 = 0, bp1 = 0, bp2 = 0, km = 0;
    unsigned int lpLo = 0, lpHi = 0;
    #pragma unroll
    for (int it = 0; it < VITER; ++it) {
        const int*   labA = (const int*)&LB[it];
        const float* tmA  = (const float*)&TM[it];
        const float* knA  = (const float*)&KN[it];
        #pragma unroll
        for (int c = 0; c < 4; ++c) {
            const int px = it * 4 + c;               // compile-time
            const int lf  = (tmA[c] > 0.5f) ? labA[c] : 0;
            const bool kb = (knA[c] > 0.5f);
            bp0 |= (lf & 1) << px;
            bp1 |= ((lf >> 1) & 1) << px;
            bp2 |= ((lf >> 2) & 1) << px;
            km  |= (kb ? 1 : 0) << px;
            if (px < 8) lpLo |= (unsigned int)lf << (4 * px);
            else        lpHi |= (unsigned int)lf << (4 * (px - 8));
        }
    }

    // ---- cluster B: 8 emb half-1 loads (px 8..15) ----
    float4 E1[2][D_];
    #pragma unroll
    for (int s = 0; s < 2; ++s)
        #pragma unroll
        for (int d = 0; d < D_; ++d)
            E1[s][d] = gload4f(embb + d * HW_ + o0 + (2 + s) * (BLOCK * 4));

    WAITCNT(8);                      // <=8 out -> half-0's 8 done (older)

    // ---- sm accumulate half 0 (half 1 latency hides under these FMAs) ----
    float sm[NL][D_];
    #pragma unroll
    for (int l = 0; l < NL; ++l)
        #pragma unroll
        for (int d = 0; d < D_; ++d) sm[l][d] = 0.f;

    #pragma unroll
    for (int s = 0; s < 2; ++s) {
        const float* e0A = (const float*)&E0[s][0];
        const float* e1A = (const float*)&E0[s][1];
        const float* e2A = (const float*)&E0[s][2];
        const float* e3A = (const float*)&E0[s][3];
        #pragma unroll
        for (int c = 0; c < 4; ++c) {
            const int px  = s * 4 + c;               // 0..7
            const int lf  = (int)((lpLo >> (4 * px)) & 7u);
            const int lfk = ((km >> px) & 1) ? lf : 0;
            #pragma unroll
            for (int l = 1; l < L_; ++l) {
                const float mk = (lfk == l) ? 1.0f : 0.0f;
                sm[l - 1][0] += mk * e0A[c];
                sm[l - 1][1] += mk * e1A[c];
                sm[l - 1][2] += mk * e2A[c];
                sm[l - 1][3] += mk * e3A[c];
            }
        }
    }

    WAITCNT(0);                      // half-1 done

    #pragma unroll
    for (int s = 0; s < 2; ++s) {
        const float* e0A = (const float*)&E1[s][0];
        const float* e1A = (const float*)&E1[s][1];
        const float* e2A = (const float*)&E1[s][2];
        const float* e3A = (const float*)&E1[s][3];
        #pragma unroll
        for (int c = 0; c < 4; ++c) {
            const int px  = 8 + s * 4 + c;           // 8..15
            const int nib = s * 4 + c;
            const int lf  = (int)((lpHi >> (4 * nib)) & 7u);
            const int lfk = ((km >> px) & 1) ? lf : 0;
            #pragma unroll
            for (int l = 1; l < L_; ++l) {
                const float mk = (lfk == l) ? 1.0f : 0.0f;
                sm[l - 1][0] += mk * e0A[c];
                sm[l - 1][1] += mk * e1A[c];
                sm[l - 1][2] += mk * e2A[c];
                sm[l - 1][3] += mk * e3A[c];
            }
        }
    }

    // ---- per-thread counts + first/second from bit-planes ----
    const int nb0 = ~bp0, nb1 = ~bp1, nb2 = ~bp2;
    int cnt[NL], m1[NL], m2[NL];
    #pragma unroll
    for (int l = 1; l < L_; ++l) {
        const int k = l - 1;
        int h = ((l & 1) ? bp0 : nb0) & ((l & 2) ? bp1 : nb1) & ((l & 4) ? bp2 : nb2);
        h &= 0xFFFF;
        cnt[k] = (__popc(h) << 16) | __popc(h & km);
        const int h2 = h & (h - 1);
        const int p1 = __ffs(h) - 1;      // valid only if h
        const int p2 = __ffs(h2) - 1;
        // px -> pixel index: o0 + (px>>2)*BLOCK*4 + (px&3), monotone in px
        m1[k] = h  ? (o0 + (p1 >> 2) * (BLOCK * 4) + (p1 & 3)) : HW_;
        m2[k] = h2 ? (o0 + (p2 >> 2) * (BLOCK * 4) + (p2 & 3)) : HW_;
    }

    // ---- 64-lane butterfly (49 values, valid at lane 0) ----
    #pragma unroll
    for (int l = 0; l < NL; ++l) {
        #pragma unroll
        for (int off = 32; off > 0; off >>= 1) {
            cnt[l]   += __shfl_down(cnt[l], off);
            sm[l][0] += __shfl_down(sm[l][0], off);
            sm[l][1] += __shfl_down(sm[l][1], off);
            sm[l][2] += __shfl_down(sm[l][2], off);
            sm[l][3] += __shfl_down(sm[l][3], off);
            int o1 = __shfl_down(m1[l], off);
            int o2 = __shfl_down(m2[l], off);
            m2[l] = min(min(m2[l], o2), max(m1[l], o1));   // two-min combine
            m1[l] = min(m1[l], o1);
        }
    }
    if (lane == 0) {
        #pragma unroll
        for (int l = 0; l < NL; ++l) {
            atomicAdd(&sCnt[l + 1], cnt[l]);   // fields <= 4096, no overflow
            #pragma unroll
            for (int d = 0; d < D_; ++d) atomicAdd(&sSum[(l + 1) * D_ + d], sm[l][d]);
            int old = atomicMin(&sM1[l + 1], m1[l]);
            atomicMin(&sM2[l + 1], max(old, m1[l]));
            atomicMin(&sM2[l + 1], m2[l]);
        }
    }
    __syncthreads();

    if (tid >= 1 && tid < L_) {
        const int pc = sCnt[tid];
        atomicAdd(&cntf_i[b * L_ + tid], pc >> 16);
        atomicAdd(&cntk_i[b * L_ + tid], pc & 0xFFFF);
        int old = atomicMin(&firstIdx[b * L_ + tid], sM1[tid]);
        atomicMin(&secondIdx[b * L_ + tid], max(old, sM1[tid]));
        atomicMin(&secondIdx[b * L_ + tid], sM2[tid]);
    }
    if (tid >= D_ && tid < L_ * D_)
        gatom_add(&sumemb[b * L_ * D_ + tid], sSum[tid]);

    // ============ per-image software barrier (graph-capture safe) ==========
    __syncthreads();                    // wave drains vmcnt before s_barrier
    if (tid == 0) {
        __threadfence();                // release our updates device-wide
        int prev = __hip_atomic_fetch_add(&barCnt[b], 1, __ATOMIC_ACQ_REL,
                                          __HIP_MEMORY_SCOPE_AGENT);
        if (prev == GRIDX - 1) {
            __hip_atomic_store(&barFlag[b], 1, __ATOMIC_RELEASE,
                               __HIP_MEMORY_SCOPE_AGENT);
        } else {
            while (__hip_atomic_load(&barFlag[b], __ATOMIC_ACQUIRE,
                                     __HIP_MEMORY_SCOPE_AGENT) == 0)
                __builtin_amdgcn_s_sleep(2);
        }
    }
    __syncthreads();

    // ---- phase 2: l_agg; labels from registers, emb re-read (L3-warm) ----
    if (tid < L_) {
        float4 mu = {0.f, 0.f, 0.f, 0.f};
        float cd = 0.f, inv = 0.f;
        if (tid > 0) {
            const float invk = 1.0f / fmaxf((float)aload_i(&cntk_i[b * L_ + tid]), 1.0f);
            mu.x = aload_f(&sumemb[b * L_ * D_ + tid * D_ + 0]) * invk;
            mu.y = aload_f(&sumemb[b * L_ * D_ + tid * D_ + 1]) * invk;
            mu.z = aload_f(&sumemb[b * L_ * D_ + tid * D_ + 2]) * invk;
            mu.w = aload_f(&sumemb[b * L_ * D_ + tid * D_ + 3]) * invk;
            const float diag = sqrtf((float)(H_ * H_ + W_ * W_));
            int f = min(aload_i(&firstIdx[b * L_ + tid]),  HW_ - 1);
            int s = min(aload_i(&secondIdx[b * L_ + tid]), HW_ - 1);
            float r0 = (float)(f / W_), c0 = (float)(f % W_);
            float r1 = (float)(s / W_), c1 = (float)(s % W_);
            cd = __expf(sqrtf((r0 - c0) * (r0 - c0) + (r1 - c1) * (r1 - c1))
                        / diag * 0.5f);
            inv = 1.0f / fmaxf((float)aload_i(&cntf_i[b * L_ + tid]), 1.0f);
        }
        sMean[tid] = mu; sCd[tid] = cd; sInv[tid] = inv;
        if (tid == 0) sAcc = 0.f;
    }
    __syncthreads();   // drains all vmem -> phase-2 vmcnt accounting is clean

    // ---- asm cluster: 16 emb loads, 4-deep counted pipeline ----
    float4 E[VITER][D_];
    #pragma unroll
    for (int it = 0; it < VITER; ++it)
        #pragma unroll
        for (int d = 0; d < D_; ++d)
            E[it][d] = gload4f(embb + d * HW_ + o0 + it * (BLOCK * 4));

    float acc = 0.f;
    #pragma unroll
    for (int it = 0; it < VITER; ++it) {
        // 16 issued; before it k: wait vmcnt(12-4k) -> E[0..k] done
        if (it == 0) { WAITCNT(12); }
        else if (it == 1) { WAITCNT(8); }
        else if (it == 2) { WAITCNT(4); }
        else { WAITCNT(0); }

        const float* e0A = (const float*)&E[it][0];
        const float* e1A = (const float*)&E[it][1];
        const float* e2A = (const float*)&E[it][2];
        const float* e3A = (const float*)&E[it][3];
        #pragma unroll
        for (int c = 0; c < 4; ++c) {
            const int px = it * 4 + c;
            const int lf = (int)(((px < 8) ? (lpLo >> (4 * px))
                                           : (lpHi >> (4 * (px - 8)))) & 7u);
            const float4 mu = sMean[lf];     // 8 float4 = 32 banks: conflict-free
            float dx = e0A[c] - mu.x, dy = e1A[c] - mu.y;
            float dz = e2A[c] - mu.z, dw = e3A[c] - mu.w;
            float d2 = dx * dx + dy * dy + dz * dz + dw * dw;
            float x  = fmaxf(sCd[lf] * sqrtf(d2) - 0.5f, 0.0f);  // lf==0 -> 0
            acc += __logf(x * x + 1.0f) * sInv[lf];
        }
    }

    #pragma unroll
    for (int off = 32; off > 0; off >>= 1)
        acc += __shfl_down(acc, off);
    if ((tid & 63) == 0) atomicAdd(&sAcc, acc);
    __syncthreads();
    if (tid == 0) gatom_add(&sumvalb[b], sAcc);
}

// ---------------------------------------------------------------------------
// K4: parallel epilogue — one thread per (b, i, j) term.
// ---------------------------------------------------------------------------
__global__ __launch_bounds__(512) void k_final(
        const int* __restrict__ firstIdx, const int* __restrict__ secondIdx,
        const int* __restrict__ cntk_i, const float* __restrict__ sumemb,
        const float* __restrict__ sumvalb, float* __restrict__ out) {
    __shared__ float sWave[8];
    const int tid = threadIdx.x;
    const int b = tid >> 6, ij = tid & 63, i = ij >> 3, j = ij & 7;
    const float diag = sqrtf((float)(H_ * H_ + W_ * W_));

    float mi[D_], mj[D_];
    {
        float ci = 1.0f / fmaxf((float)cntk_i[b * L_ + i], 1.0f);
        float cj = 1.0f / fmaxf((float)cntk_i[b * L_ + j], 1.0f);
        #pragma unroll
        for (int d = 0; d < D_; ++d) {
            mi[d] = (i > 0) ? sumemb[(b * L_ + i) * D_ + d] * ci : 0.0f;
            mj[d] = (j > 0) ? sumemb[(b * L_ + j) * D_ + d] * cj : 0.0f;
        }
    }

    float contrib = 0.0f;
    if (j == 0) {            // l_reg term for label i (i=0 gives 0)
        float d2 = 0.f;
        #pragma unroll
        for (int d = 0; d < D_; ++d) d2 += mi[d] * mi[d];
        float n = (d2 > 0.f) ? sqrtf(d2) : 0.f;
        contrib += __logf(n + 1.0f) * (0.001f / (float)L_);
    }
    if (i == 0 && j == 1)    // l_agg (already /cntf per label)
        contrib += sumvalb[b] * (1.0f / (float)NL);
    if (i >= 1 && j >= 1 && i != j) {   // l_dis pair term
        float d2 = 0.f;
        #pragma unroll
        for (int d = 0; d < D_; ++d) {
            float df = mi[d] - mj[d];
            d2 += df * df;
        }
        float Dn = (d2 > 0.f) ? sqrtf(d2) : 0.f;
        int fi = min(firstIdx[b * L_ + i],  HW_ - 1);
        int si = min(secondIdx[b * L_ + i], HW_ - 1);
        int fj = min(firstIdx[b * L_ + j],  HW_ - 1);
        int sj = min(secondIdx[b * L_ + j], HW_ - 1);
        float ssi = (float)(fi / W_) + (float)(fi % W_);
        float tti = (float)(si / W_) + (float)(si % W_);
        float ssj = (float)(fj / W_) + (float)(fj % W_);
        float ttj = (float)(sj / W_) + (float)(sj % W_);
        float dx = ssi - ssj, dy = tti - ttj;
        float dp = sqrtf(dx * dx + dy * dy);
        float coef = 1.0f - 20.0f * __expf(-4.0f - 2.5f * dp / diag);
        float x = fmaxf(3.0f - coef * Dn, 0.0f);   // 2*delta_d = 3.0
        contrib += __logf(x * x + 1.0f) * (1.0f / 42.0f);
    }

    #pragma unroll
    for (int off = 32; off > 0; off >>= 1)
        contrib += __shfl_down(contrib, off);
    if ((tid & 63) == 0) sWave[tid >> 6] = contrib;
    __syncthreads();
    if (tid == 0) {
        float t = 0.f;
        #pragma unroll
        for (int w = 0; w < 8; ++w) t += sWave[w];
        out[0] = t * (1.0f / (float)B_);           // LOSS_WEIGHT = 1
    }
}

extern "C" void kernel_launch(void* const* d_in, const int* in_sizes, int n_in,
                              void* d_out, int out_size, void* d_ws, size_t ws_size,
                              hipStream_t stream) {
    const float* emb   = (const float*)d_in[0];
    const int*   inst  = (const int*)  d_in[1];
    const float* kern  = (const float*)d_in[2];
    const float* tmask = (const float*)d_in[3];
    // d_in[4] = bboxes, unused by the reference

    int*   ib        = (int*)d_ws;
    int*   firstIdx  = ib;
    int*   secondIdx = ib + 64;
    int*   cntf_i    = ib + 128;
    int*   cntk_i    = ib + 192;
    float* sumemb    = (float*)(ib + 256);
    float* sumvalb   = (float*)(ib + 512);
    int*   barCnt    = ib + 544;
    int*   barFlag   = ib + 552;
    float* out       = (float*)d_out;

    dim3 grid(GRIDX, B_);   // (100, 8) = 800 blocks, all co-resident

    k_init <<<1, 256, 0, stream>>>(ib);
    k_fused<<<grid, BLOCK, 0, stream>>>(emb, inst, kern, tmask,
                                        firstIdx, secondIdx, cntf_i, cntk_i,
                                        sumemb, sumvalb, barCnt, barFlag);
    k_final<<<1, 512, 0, stream>>>(firstIdx, secondIdx, cntk_i,
                                   sumemb, sumvalb, out);
}

// Round 10
// 147.760 us; speedup vs baseline: 1.8396x; 1.8396x over previous
//
#include <hip/hip_runtime.h>

// Problem constants (fixed by setup_inputs)
#define B_    8
#define D_    4
#define H_    640
#define W_    640
#define HW_   (H_ * W_)      // 409600
#define L_    8
#define NL    (L_ - 1)       // labels 1..7
#define BLOCK 256
#define VITER 4              // float4 iterations per thread -> 16 px/thread
#define PXB   (BLOCK * 4 * VITER)           // 4096 px per block
#define GRIDX (HW_ / PXB)                   // 100 -> grid (100,8) = 800 blocks

__device__ __forceinline__ void gatom_add(float* p, float v) {
    unsafeAtomicAdd(p, v);   // global_atomic_add_f32
}

// ---------------------------------------------------------------------------
// ws layout (4-byte elements):
//   int   firstIdx [64] @0     int secondIdx[64] @64
//   int   cntf_i   [64] @128   int cntk_i   [64] @192
//   float sumemb  [256] @256   float sumvalb [8] @512
//   uint2 lblpack  [204800] @1024  (16 x 4-bit labels per thread)
// ---------------------------------------------------------------------------
__global__ void k_init(int* ib) {
    int t = threadIdx.x;
    if (t < 128) ib[t] = HW_;        // firstIdx + secondIdx
    ib[128 + t] = 0;                 // 128..383
    if (t < 137) ib[384 + t] = 0;    // 384..520
}

// ---------------------------------------------------------------------------
// K1 (final = R4, best measured 148.2us total): phase-split load schedule.
//  Session findings (R0-R9): pass1 is pinned at ~42.5us across SIX schedule
//  variants — the HIP IR sinks C loads into uses regardless of source
//  order/sched_barrier, and the backend inserts conservative waits around
//  inline-asm loads, so per-thread MLP cannot be raised at source level.
//  Per-byte rate (2.2 TB/s read) is invariant to wave count (R2: 2x blocks
//  -> slower) and to LDS-atomic restructuring (R3: RMW chains 2x slower).
//  Fusion with pass3 fails all three ways: cooperative launch is dropped
//  by graph capture (R1), register-carry spills wholesale (R5/R6), and a
//  software grid barrier costs ~95-100us at this grid size (R9).
// ---------------------------------------------------------------------------
__global__ __attribute__((amdgpu_flat_work_group_size(BLOCK, BLOCK),
                          amdgpu_waves_per_eu(4, 8)))
void k_pass1(
        const float* __restrict__ emb, const int* __restrict__ inst,
        const float* __restrict__ kern, const float* __restrict__ tmask,
        int* __restrict__ firstIdx, int* __restrict__ secondIdx,
        int* __restrict__ cntf_i, int* __restrict__ cntk_i,
        float* __restrict__ sumemb, uint2* __restrict__ lblpack) {
    __shared__ int   sCnt[L_];       // cf<<16 | ck
    __shared__ float sSum[L_ * D_];
    __shared__ int   sM1[L_], sM2[L_];

    const int tid  = threadIdx.x;
    const int lane = tid & 63;
    if (tid < L_) { sCnt[tid] = 0; sM1[tid] = HW_; sM2[tid] = HW_; }
    if (tid < L_ * D_) sSum[tid] = 0.f;
    __syncthreads();

    const int b = blockIdx.y;
    const int blockbase = blockIdx.x * PXB;
    const float* embb = emb + (size_t)b * D_ * HW_;
    const int base = b * HW_;
    const int o0 = blockbase + tid * 4;

    // ---- (1) all mask loads first ----
    int4 LB[VITER]; float4 TM[VITER], KN[VITER];
    #pragma unroll
    for (int it = 0; it < VITER; ++it) {
        const int o = o0 + it * (BLOCK * 4);
        LB[it] = *(const int4*)  (inst  + base + o);
        TM[it] = *(const float4*)(tmask + base + o);
        KN[it] = *(const float4*)(kern  + base + o);
    }
    // ---- emb half 0 (px 0..7, it = 0,1) ----
    float4 E[2][2][D_];              // [half][sub-it][d]
    #pragma unroll
    for (int s = 0; s < 2; ++s)
        #pragma unroll
        for (int d = 0; d < D_; ++d)
            E[0][s][d] = *(const float4*)(embb + d * HW_ + o0 + s * (BLOCK * 4));

    // ---- (2) bitplanes + packed labels for all 16 px ----
    int bp0 = 0, bp1 = 0, bp2 = 0, km = 0;
    unsigned int lpLo = 0, lpHi = 0;
    #pragma unroll
    for (int it = 0; it < VITER; ++it) {
        const int*   labA = (const int*)&LB[it];
        const float* tmA  = (const float*)&TM[it];
        const float* knA  = (const float*)&KN[it];
        #pragma unroll
        for (int c = 0; c < 4; ++c) {
            const int px = it * 4 + c;               // compile-time
            const int lf  = (tmA[c] > 0.5f) ? labA[c] : 0;
            const bool kb = (knA[c] > 0.5f);
            bp0 |= (lf & 1) << px;
            bp1 |= ((lf >> 1) & 1) << px;
            bp2 |= ((lf >> 2) & 1) << px;
            km  |= (kb ? 1 : 0) << px;
            if (px < 8) lpLo |= (unsigned int)lf << (4 * px);
            else        lpHi |= (unsigned int)lf << (4 * (px - 8));
        }
    }

    // export packed labels for pass3 (same thread/block mapping there)
    lblpack[(size_t)(b * GRIDX + blockIdx.x) * BLOCK + tid] = make_uint2(lpLo, lpHi);

    // ---- (3) emb half 1 (px 8..15, it = 2,3) ----
    #pragma unroll
    for (int s = 0; s < 2; ++s)
        #pragma unroll
        for (int d = 0; d < D_; ++d)
            E[1][s][d] = *(const float4*)(embb + d * HW_ + o0 + (2 + s) * (BLOCK * 4));

    // ---- (4) masked per-label sums from registers ----
    float sm[NL][D_];
    #pragma unroll
    for (int l = 0; l < NL; ++l)
        #pragma unroll
        for (int d = 0; d < D_; ++d) sm[l][d] = 0.f;

    #pragma unroll
    for (int half = 0; half < 2; ++half) {
        const unsigned int lp = half ? lpHi : lpLo;
        #pragma unroll
        for (int s = 0; s < 2; ++s) {
            const float* e0A = (const float*)&E[half][s][0];
            const float* e1A = (const float*)&E[half][s][1];
            const float* e2A = (const float*)&E[half][s][2];
            const float* e3A = (const float*)&E[half][s][3];
            #pragma unroll
            for (int c = 0; c < 4; ++c) {
                const int px  = half * 8 + s * 4 + c;        // compile-time
                const int nib = s * 4 + c;                   // nibble in lp
                const int lf  = (int)((lp >> (4 * nib)) & 7u);
                const int lfk = ((km >> px) & 1) ? lf : 0;
                #pragma unroll
                for (int l = 1; l < L_; ++l) {
                    const float mk = (lfk == l) ? 1.0f : 0.0f;
                    sm[l - 1][0] += mk * e0A[c];
                    sm[l - 1][1] += mk * e1A[c];
                    sm[l - 1][2] += mk * e2A[c];
                    sm[l - 1][3] += mk * e3A[c];
                }
            }
        }
    }

    // ---- per-thread counts + first/second from bit-planes ----
    const int nb0 = ~bp0, nb1 = ~bp1, nb2 = ~bp2;
    int cnt[NL], m1[NL], m2[NL];
    #pragma unroll
    for (int l = 1; l < L_; ++l) {
        const int k = l - 1;
        int h = ((l & 1) ? bp0 : nb0) & ((l & 2) ? bp1 : nb1) & ((l & 4) ? bp2 : nb2);
        h &= 0xFFFF;
        cnt[k] = (__popc(h) << 16) | __popc(h & km);
        const int h2 = h & (h - 1);
        const int p1 = __ffs(h) - 1;      // valid only if h
        const int p2 = __ffs(h2) - 1;
        // px -> pixel index: o0 + (px>>2)*BLOCK*4 + (px&3), monotone in px
        m1[k] = h  ? (o0 + (p1 >> 2) * (BLOCK * 4) + (p1 & 3)) : HW_;
        m2[k] = h2 ? (o0 + (p2 >> 2) * (BLOCK * 4) + (p2 & 3)) : HW_;
    }

    // ---- 64-lane butterfly (49 values, valid at lane 0) ----
    #pragma unroll
    for (int l = 0; l < NL; ++l) {
        #pragma unroll
        for (int off = 32; off > 0; off >>= 1) {
            cnt[l]   += __shfl_down(cnt[l], off);
            sm[l][0] += __shfl_down(sm[l][0], off);
            sm[l][1] += __shfl_down(sm[l][1], off);
            sm[l][2] += __shfl_down(sm[l][2], off);
            sm[l][3] += __shfl_down(sm[l][3], off);
            int o1 = __shfl_down(m1[l], off);
            int o2 = __shfl_down(m2[l], off);
            m2[l] = min(min(m2[l], o2), max(m1[l], o1));   // two-min combine
            m1[l] = min(m1[l], o1);
        }
    }
    if (lane == 0) {
        #pragma unroll
        for (int l = 0; l < NL; ++l) {
            atomicAdd(&sCnt[l + 1], cnt[l]);   // fields <= 4096, no overflow
            #pragma unroll
            for (int d = 0; d < D_; ++d) atomicAdd(&sSum[(l + 1) * D_ + d], sm[l][d]);
            int old = atomicMin(&sM1[l + 1], m1[l]);
            atomicMin(&sM2[l + 1], max(old, m1[l]));
            atomicMin(&sM2[l + 1], m2[l]);
        }
    }
    __syncthreads();

    if (tid >= 1 && tid < L_) {
        const int pc = sCnt[tid];
        atomicAdd(&cntf_i[b * L_ + tid], pc >> 16);
        atomicAdd(&cntk_i[b * L_ + tid], pc & 0xFFFF);
        int old = atomicMin(&firstIdx[b * L_ + tid], sM1[tid]);
        atomicMin(&secondIdx[b * L_ + tid], max(old, sM1[tid]));
        atomicMin(&secondIdx[b * L_ + tid], sM2[tid]);
    }
    if (tid >= D_ && tid < L_ * D_)
        gatom_add(&sumemb[b * L_ * D_ + tid], sSum[tid]);
}

// ---------------------------------------------------------------------------
// K3: l_agg — proven R0/R4 version (~20us, 2.75 TB/s): reads emb + packed
// labels only; all 17 loads issued up front under the (4,4) pinned budget;
// single scalar accumulator (val * 1/cntf[lf]).
// ---------------------------------------------------------------------------
__global__ __attribute__((amdgpu_flat_work_group_size(BLOCK, BLOCK),
                          amdgpu_waves_per_eu(4, 4)))
void k_pass3(
        const float* __restrict__ emb, const uint2* __restrict__ lblpack,
        const int* __restrict__ firstIdx, const int* __restrict__ secondIdx,
        const int* __restrict__ cntk_i, const int* __restrict__ cntf_i,
        const float* __restrict__ sumemb, float* __restrict__ sumvalb) {
    __shared__ float4 sMean[L_];
    __shared__ float  sCd[L_], sInv[L_];
    __shared__ float  sAcc;

    const int tid = threadIdx.x;
    const int b   = blockIdx.y;

    if (tid < L_) {
        float4 mu = {0.f, 0.f, 0.f, 0.f};
        float cd = 0.f, inv = 0.f;
        if (tid > 0) {
            const float invk = 1.0f / fmaxf((float)cntk_i[b * L_ + tid], 1.0f);
            mu.x = sumemb[b * L_ * D_ + tid * D_ + 0] * invk;
            mu.y = sumemb[b * L_ * D_ + tid * D_ + 1] * invk;
            mu.z = sumemb[b * L_ * D_ + tid * D_ + 2] * invk;
            mu.w = sumemb[b * L_ * D_ + tid * D_ + 3] * invk;
            const float diag = sqrtf((float)(H_ * H_ + W_ * W_));
            int f = min(firstIdx[b * L_ + tid],  HW_ - 1);
            int s = min(secondIdx[b * L_ + tid], HW_ - 1);
            float r0 = (float)(f / W_), c0 = (float)(f % W_);
            float r1 = (float)(s / W_), c1 = (float)(s % W_);
            cd = __expf(sqrtf((r0 - c0) * (r0 - c0) + (r1 - c1) * (r1 - c1))
                        / diag * 0.5f);
            inv = 1.0f / fmaxf((float)cntf_i[b * L_ + tid], 1.0f);
        }
        sMean[tid] = mu; sCd[tid] = cd; sInv[tid] = inv;
        if (tid == 0) sAcc = 0.f;
    }
    __syncthreads();

    const int blockbase = blockIdx.x * PXB;
    const float* embb = emb + (size_t)b * D_ * HW_;
    const int o0 = blockbase + tid * 4;

    // ---- all loads up front ----
    const uint2 lp = lblpack[(size_t)(b * GRIDX + blockIdx.x) * BLOCK + tid];
    float4 E[VITER][D_];
    #pragma unroll
    for (int it = 0; it < VITER; ++it)
        #pragma unroll
        for (int d = 0; d < D_; ++d)
            E[it][d] = *(const float4*)(embb + d * HW_ + o0 + it * (BLOCK * 4));

    float acc = 0.f;
    #pragma unroll
    for (int it = 0; it < VITER; ++it) {
        const float* e0A = (const float*)&E[it][0];
        const float* e1A = (const float*)&E[it][1];
        const float* e2A = (const float*)&E[it][2];
        const float* e3A = (const float*)&E[it][3];
        #pragma unroll
        for (int c = 0; c < 4; ++c) {
            const int px = it * 4 + c;
            const int lf = (int)(((px < 8) ? (lp.x >> (4 * px))
                                           : (lp.y >> (4 * (px - 8)))) & 7u);
            const float4 mu = sMean[lf];     // 8 float4 = 32 banks: conflict-free
            float dx = e0A[c] - mu.x, dy = e1A[c] - mu.y;
            float dz = e2A[c] - mu.z, dw = e3A[c] - mu.w;
            float d2 = dx * dx + dy * dy + dz * dz + dw * dw;
            float x  = fmaxf(sCd[lf] * sqrtf(d2) - 0.5f, 0.0f);  // lf==0 -> 0
            acc += __logf(x * x + 1.0f) * sInv[lf];
        }
    }

    #pragma unroll
    for (int off = 32; off > 0; off >>= 1)
        acc += __shfl_down(acc, off);
    if ((tid & 63) == 0) atomicAdd(&sAcc, acc);
    __syncthreads();
    if (tid == 0) gatom_add(&sumvalb[b], sAcc);
}

// ---------------------------------------------------------------------------
// K4: parallel epilogue — one thread per (b, i, j) term.
// ---------------------------------------------------------------------------
__global__ __launch_bounds__(512) void k_final(
        const int* __restrict__ firstIdx, const int* __restrict__ secondIdx,
        const int* __restrict__ cntk_i, const float* __restrict__ sumemb,
        const float* __restrict__ sumvalb, float* __restrict__ out) {
    __shared__ float sWave[8];
    const int tid = threadIdx.x;
    const int b = tid >> 6, ij = tid & 63, i = ij >> 3, j = ij & 7;
    const float diag = sqrtf((float)(H_ * H_ + W_ * W_));

    float mi[D_], mj[D_];
    {
        float ci = 1.0f / fmaxf((float)cntk_i[b * L_ + i], 1.0f);
        float cj = 1.0f / fmaxf((float)cntk_i[b * L_ + j], 1.0f);
        #pragma unroll
        for (int d = 0; d < D_; ++d) {
            mi[d] = (i > 0) ? sumemb[(b * L_ + i) * D_ + d] * ci : 0.0f;
            mj[d] = (j > 0) ? sumemb[(b * L_ + j) * D_ + d] * cj : 0.0f;
        }
    }

    float contrib = 0.0f;
    if (j == 0) {            // l_reg term for label i (i=0 gives 0)
        float d2 = 0.f;
        #pragma unroll
        for (int d = 0; d < D_; ++d) d2 += mi[d] * mi[d];
        float n = (d2 > 0.f) ? sqrtf(d2) : 0.f;
        contrib += __logf(n + 1.0f) * (0.001f / (float)L_);
    }
    if (i == 0 && j == 1)    // l_agg (already /cntf per label)
        contrib += sumvalb[b] * (1.0f / (float)NL);
    if (i >= 1 && j >= 1 && i != j) {   // l_dis pair term
        float d2 = 0.f;
        #pragma unroll
        for (int d = 0; d < D_; ++d) {
            float df = mi[d] - mj[d];
            d2 += df * df;
        }
        float Dn = (d2 > 0.f) ? sqrtf(d2) : 0.f;
        int fi = min(firstIdx[b * L_ + i],  HW_ - 1);
        int si = min(secondIdx[b * L_ + i], HW_ - 1);
        int fj = min(firstIdx[b * L_ + j],  HW_ - 1);
        int sj = min(secondIdx[b * L_ + j], HW_ - 1);
        float ssi = (float)(fi / W_) + (float)(fi % W_);
        float tti = (float)(si / W_) + (float)(si % W_);
        float ssj = (float)(fj / W_) + (float)(fj % W_);
        float ttj = (float)(sj / W_) + (float)(sj % W_);
        float dx = ssi - ssj, dy = tti - ttj;
        float dp = sqrtf(dx * dx + dy * dy);
        float coef = 1.0f - 20.0f * __expf(-4.0f - 2.5f * dp / diag);
        float x = fmaxf(3.0f - coef * Dn, 0.0f);   // 2*delta_d = 3.0
        contrib += __logf(x * x + 1.0f) * (1.0f / 42.0f);
    }

    #pragma unroll
    for (int off = 32; off > 0; off >>= 1)
        contrib += __shfl_down(contrib, off);
    if ((tid & 63) == 0) sWave[tid >> 6] = contrib;
    __syncthreads();
    if (tid == 0) {
        float t = 0.f;
        #pragma unroll
        for (int w = 0; w < 8; ++w) t += sWave[w];
        out[0] = t * (1.0f / (float)B_);           // LOSS_WEIGHT = 1
    }
}

extern "C" void kernel_launch(void* const* d_in, const int* in_sizes, int n_in,
                              void* d_out, int out_size, void* d_ws, size_t ws_size,
                              hipStream_t stream) {
    const float* emb   = (const float*)d_in[0];
    const int*   inst  = (const int*)  d_in[1];
    const float* kern  = (const float*)d_in[2];
    const float* tmask = (const float*)d_in[3];
    // d_in[4] = bboxes, unused by the reference

    int*   ib        = (int*)d_ws;
    int*   firstIdx  = ib;
    int*   secondIdx = ib + 64;
    int*   cntf_i    = ib + 128;
    int*   cntk_i    = ib + 192;
    float* sumemb    = (float*)(ib + 256);
    float* sumvalb   = (float*)(ib + 512);
    uint2* lblpack   = (uint2*)(ib + 1024);
    float* out       = (float*)d_out;

    dim3 grid(GRIDX, B_);   // (100, 8) = 800 blocks

    k_init <<<1, 256, 0, stream>>>(ib);
    k_pass1<<<grid, BLOCK, 0, stream>>>(emb, inst, kern, tmask,
                                        firstIdx, secondIdx, cntf_i, cntk_i,
                                        sumemb, lblpack);
    k_pass3<<<grid, BLOCK, 0, stream>>>(emb, lblpack, firstIdx, secondIdx,
                                        cntk_i, cntf_i, sumemb, sumvalb);
    k_final<<<1, 512, 0, stream>>>(firstIdx, secondIdx, cntk_i,
                                   sumemb, sumvalb, out);
}